// Round 8
// baseline (1973.573 us; speedup 1.0000x reference)
//
#include <hip/hip_runtime.h>

#define HID 1024
#define AL  128
#define OPS 16
#define GS  32
#define NBLK 256
#define TPB  256

// ws layout (float offsets)
#define WS_HBUF    0         // [2 layers][2 bufs][1024]
#define WS_OUTMAIN 4096      // [128][1024]
#define WS_OUTGAP  135168    // [128][1024]
#define WS_PE      266240    // [128]
#define WS_PL      266368    // [128]
#define WS_CNT     266496    // 256 per-block epoch slots (uint)

__device__ __forceinline__ float sig_(float x) { return 1.0f / (1.0f + expf(-x)); }

// Coherence-point (L3) access helpers: sc0 sc1 bypass L1 + non-coherent L2.
__device__ __forceinline__ void st_coh(float* p, float v) {
    asm volatile("global_store_dword %0, %1, off sc0 sc1" :: "v"(p), "v"(v) : "memory");
}
__device__ __forceinline__ void st_coh_u(unsigned* p, unsigned v) {
    asm volatile("global_store_dword %0, %1, off sc0 sc1" :: "v"(p), "v"(v) : "memory");
}
__device__ __forceinline__ void ld_coh_issue(float4& dst, const float4* p) {
    asm volatile("global_load_dwordx4 %0, %1, off sc0 sc1" : "=v"(dst) : "v"(p) : "memory");
}
__device__ __forceinline__ unsigned ld_coh_u(const unsigned* p) {
    unsigned r;
    asm volatile("global_load_dword %0, %1, off sc0 sc1" : "=v"(r) : "v"(p) : "memory");
    return r;
}
// Drain outstanding vm ops; sched_barrier stops the compiler from hoisting
// dependent uses above the wait (rule #18).
__device__ __forceinline__ void wait_vm0() {
    asm volatile("s_waitcnt vmcnt(0)" ::: "memory");
    __builtin_amdgcn_sched_barrier(0);
}

__global__ void k_init(float* ws) {
    const int i = blockIdx.x * blockDim.x + threadIdx.x;
    if (i < 4096) ws[WS_HBUF + i] = 0.f;                 // h double-buffers
    if (i < 1024) ((unsigned*)(ws + WS_CNT))[i] = 0u;    // epoch slots
}

#define WIDX(l, r, k, c) ((((l) * 4 + (r)) * 8 + (k)) * 4 + (c))

// One LSTM layer-cell, fence-free slot-barrier protocol:
//  stage x (fresh L3 read) + h (prefetched) -> LDS -> dot with AGPR weights ->
//  butterfly -> gates -> publish h (sc0sc1) -> vmcnt(0) -> write own epoch slot
//  -> issue next-cell h prefetch -> poll all 256 slots in parallel until done.
template<int LY>
__device__ __forceinline__ void cell(
    float (&wa)[256], const float (&bs)[2][4], float (&cst)[2],
    const float*& xsrc, float* Hbuf, int& par, int otherPar,
    unsigned& nbar, unsigned* slots,
    int tid, int bid, int lane, int u, float* lds_cat, int* okf, float* snap,
    float4& vh_pre)
{
    // ---- stage: x fresh from L3, h from prefetch ----
    float4 vx;
    ld_coh_issue(vx, (const float4*)xsrc + tid);
    wait_vm0();                      // vx and vh_pre both resident now
    {
        float4* d = (float4*)lds_cat;
        d[tid]       = vx;
        d[256 + tid] = vh_pre;
    }
    __syncthreads();

    // ---- dot: 4 gate rows, weights from AGPRs ----
    float acc[4] = {0.f, 0.f, 0.f, 0.f};
    const float4* l4 = (const float4*)lds_cat;
#pragma unroll
    for (int k = 0; k < 8; k++) {
        float4 v = l4[lane + 64 * k];   // contiguous 1KB per instr: conflict-free
#pragma unroll
        for (int r = 0; r < 4; r++) {
            float w0, w1, w2, w3;
            asm volatile("v_accvgpr_read_b32 %0, %1" : "=v"(w0) : "a"(wa[WIDX(LY, r, k, 0)]));
            asm volatile("v_accvgpr_read_b32 %0, %1" : "=v"(w1) : "a"(wa[WIDX(LY, r, k, 1)]));
            asm volatile("v_accvgpr_read_b32 %0, %1" : "=v"(w2) : "a"(wa[WIDX(LY, r, k, 2)]));
            asm volatile("v_accvgpr_read_b32 %0, %1" : "=v"(w3) : "a"(wa[WIDX(LY, r, k, 3)]));
            acc[r] += w0 * v.x + w1 * v.y + w2 * v.z + w3 * v.w;
        }
    }
#pragma unroll
    for (int off = 32; off > 0; off >>= 1) {
        acc[0] += __shfl_xor(acc[0], off, 64);
        acc[1] += __shfl_xor(acc[1], off, 64);
        acc[2] += __shfl_xor(acc[2], off, 64);
        acc[3] += __shfl_xor(acc[3], off, 64);
    }
    const float gi = sig_(acc[0] + bs[LY][0]);
    const float gf = sig_(acc[1] + bs[LY][1]);
    const float gg = tanhf(acc[2] + bs[LY][2]);
    const float go = sig_(acc[3] + bs[LY][3]);
    const float c  = gf * cst[LY] + gi * gg;
    cst[LY] = c;
    const float h = go * tanhf(c);

    // ---- publish h at the coherence point ----
    par ^= 1;
    if (lane == 0) {
        st_coh(&Hbuf[LY * 2048 + par * 1024 + u], h);   // write-through to L3
        if (snap) snap[u] = h;                           // plain; read by next kernel
    }
    asm volatile("s_waitcnt vmcnt(0)" ::: "memory");     // h-store complete at L3
    ++nbar;

    // ---- arrive: write own epoch slot (no RMW, no contention) ----
    __syncthreads();                                     // all 4 waves' h drained
    if (tid == 0) st_coh_u(&slots[bid], nbar);
    // ---- prefetch next cell's recurrent h (published >=1 barrier ago) ----
    {
        const float4* hnext = (const float4*)(Hbuf + (1 - LY) * 2048 + otherPar * 1024);
        ld_coh_issue(vh_pre, hnext + tid);
    }
    // ---- detect: all threads poll all 256 slots in parallel ----
    const int widx = tid >> 6;
    for (;;) {
        unsigned sv = ld_coh_u(&slots[tid]);
        wait_vm0();                                      // sv (and prefetch) resident
        int ok = __all((int)(sv >= nbar));
        if (lane == 0) okf[widx] = ok;
        __syncthreads();
        int done = okf[0] & okf[1] & okf[2] & okf[3];
        __syncthreads();
        if (done) break;
    }
    xsrc = Hbuf + LY * 2048 + par * 1024;
}

__global__ __launch_bounds__(TPB, 1) void k_chain(
    const float* __restrict__ g_emb, const float* __restrict__ W_ih,
    const float* __restrict__ W_hh, const float* __restrict__ b_ih,
    const float* __restrict__ b_hh, const int* __restrict__ config, float* ws)
{
    const int tid  = threadIdx.x;
    const int bid  = blockIdx.x;
    const int lane = tid & 63;
    const int u    = bid * 4 + (tid >> 6);   // hidden unit owned by this wave

    float* Hbuf     = ws + WS_HBUF;
    float* OutMain  = ws + WS_OUTMAIN;
    float* OutGap   = ws + WS_OUTGAP;
    unsigned* slots = (unsigned*)(ws + WS_CNT);

    __shared__ float lds_cat[2048];
    __shared__ int   cfg_s[AL];
    __shared__ int   okf[4];

    // Persist weights in AGPRs: 256 fp32/lane (1 wave/SIMD -> 512-reg budget).
    float wa[256];
    float bs[2][4];
#pragma unroll
    for (int l = 0; l < 2; l++) {
#pragma unroll
        for (int r = 0; r < 4; r++) {
            const float* Wi = W_ih + (size_t)l * 4 * HID * HID + (size_t)(r * HID + u) * HID;
            const float* Wh = W_hh + (size_t)l * 4 * HID * HID + (size_t)(r * HID + u) * HID;
#pragma unroll
            for (int k = 0; k < 4; k++) {
                float4 t = *(const float4*)(Wi + 4 * lane + 256 * k);
                asm volatile("v_accvgpr_write_b32 %0, %1" : "=a"(wa[WIDX(l, r, k, 0)]) : "v"(t.x));
                asm volatile("v_accvgpr_write_b32 %0, %1" : "=a"(wa[WIDX(l, r, k, 1)]) : "v"(t.y));
                asm volatile("v_accvgpr_write_b32 %0, %1" : "=a"(wa[WIDX(l, r, k, 2)]) : "v"(t.z));
                asm volatile("v_accvgpr_write_b32 %0, %1" : "=a"(wa[WIDX(l, r, k, 3)]) : "v"(t.w));
            }
#pragma unroll
            for (int k = 0; k < 4; k++) {
                float4 t = *(const float4*)(Wh + 4 * lane + 256 * k);
                asm volatile("v_accvgpr_write_b32 %0, %1" : "=a"(wa[WIDX(l, r, k + 4, 0)]) : "v"(t.x));
                asm volatile("v_accvgpr_write_b32 %0, %1" : "=a"(wa[WIDX(l, r, k + 4, 1)]) : "v"(t.y));
                asm volatile("v_accvgpr_write_b32 %0, %1" : "=a"(wa[WIDX(l, r, k + 4, 2)]) : "v"(t.z));
                asm volatile("v_accvgpr_write_b32 %0, %1" : "=a"(wa[WIDX(l, r, k + 4, 3)]) : "v"(t.w));
            }
            bs[l][r] = b_ih[l * 4 * HID + r * HID + u] + b_hh[l * 4 * HID + r * HID + u];
        }
    }
    if (tid < AL) cfg_s[tid] = config[tid];
    __syncthreads();

    float cst[2] = {0.f, 0.f};
    int par0 = 0, par1 = 0;
    unsigned nbar = 0;
    const float* xsrc = g_emb;
    float4 vh_pre = make_float4(0.f, 0.f, 0.f, 0.f);   // first cell's h0 = zeros

    for (int t = 0; t < AL; t++) {
        cell<0>(wa, bs, cst, xsrc, Hbuf, par0, par1, nbar, slots, tid, bid, lane, u,
                lds_cat, okf, nullptr, vh_pre);
        cell<1>(wa, bs, cst, xsrc, Hbuf, par1, par0, nbar, slots, tid, bid, lane, u,
                lds_cat, okf, OutMain + t * HID, vh_pre);
        if (cfg_s[t] == 1) {   // gap pass only matters when cfg == 1
            cell<0>(wa, bs, cst, xsrc, Hbuf, par0, par1, nbar, slots, tid, bid, lane, u,
                    lds_cat, okf, nullptr, vh_pre);
            cell<1>(wa, bs, cst, xsrc, Hbuf, par1, par0, nbar, slots, tid, bid, lane, u,
                    lds_cat, okf, OutGap + t * HID, vh_pre);
        }
    }
}

__global__ void k_heads(
    const float* __restrict__ ctx_W, const float* __restrict__ ctx_b,
    const float* __restrict__ left_W, const float* __restrict__ left_b,
    const int* __restrict__ config, const int* __restrict__ left_config, float* ws)
{
    const int t   = blockIdx.x;    // 128 blocks, one per step
    const int tid = threadIdx.x;   // 256 threads
    const float* o1 = ws + WS_OUTMAIN + (size_t)t * HID;
    const float* o2 = ws + WS_OUTGAP  + (size_t)t * HID;
    const int cfg = config[t];

    __shared__ float lgm[OPS];
    __shared__ float lgg[GS];

    float ent = 0.f, lp = 0.f;
    {   // main head: 16 rows, 16 threads/row
        const int g = tid >> 4, l16 = tid & 15;
        const float* wr = ctx_W + ((size_t)t * OPS + g) * HID;
        float a = 0.f;
#pragma unroll 4
        for (int k = 0; k < 16; k++) {
            float4 wv = *(const float4*)(wr + 4 * l16 + 64 * k);
            float4 xv = *(const float4*)(o1 + 4 * l16 + 64 * k);
            a += wv.x * xv.x + wv.y * xv.y + wv.z * xv.z + wv.w * xv.w;
        }
#pragma unroll
        for (int off = 1; off < 16; off <<= 1) a += __shfl_xor(a, off, 64);
        if (l16 == 0) lgm[g] = a + ctx_b[t * OPS + g];
    }
    __syncthreads();
    if (tid == 0) {
        float m = -1e30f;
        for (int g = 0; g < OPS; g++) m = fmaxf(m, lgm[g]);
        float s = 0.f;
        for (int g = 0; g < OPS; g++) s += expf(lgm[g] - m);
        const float lse = m + logf(s);
        for (int g = 0; g < OPS; g++) { float ls = lgm[g] - lse; ent -= expf(ls) * ls; }
        lp += lgm[cfg] - lse;
    }
    if (cfg == 1) {   // gap head: 32 rows, 8 threads/row
        const int g = tid >> 3, l8 = tid & 7;
        const float* wr = left_W + ((size_t)t * GS + g) * HID;
        float a = 0.f;
#pragma unroll 4
        for (int k = 0; k < 32; k++) {
            float4 wv = *(const float4*)(wr + 4 * l8 + 32 * k);
            float4 xv = *(const float4*)(o2 + 4 * l8 + 32 * k);
            a += wv.x * xv.x + wv.y * xv.y + wv.z * xv.z + wv.w * xv.w;
        }
#pragma unroll
        for (int off = 1; off < 8; off <<= 1) a += __shfl_xor(a, off, 64);
        if (l8 == 0) lgg[g] = a + left_b[t * GS + g];
        __syncthreads();
        if (tid == 0) {
            float m = -1e30f;
            for (int g = 0; g < GS; g++) m = fmaxf(m, lgg[g]);
            float s = 0.f;
            for (int g = 0; g < GS; g++) s += expf(lgg[g] - m);
            const float lse = m + logf(s);
            for (int g = 0; g < GS; g++) { float ls = lgg[g] - lse; ent -= expf(ls) * ls; }
            lp += lgg[left_config[t]] - lse;
        }
    }
    if (tid == 0) { ws[WS_PE + t] = ent; ws[WS_PL + t] = lp; }
}

__global__ void k_reduce(const float* __restrict__ ws, float* __restrict__ out) {
    const int tid = threadIdx.x;   // 128 threads, 2 waves
    __shared__ float s4[4];
    float e = ws[WS_PE + tid], p = ws[WS_PL + tid];
#pragma unroll
    for (int off = 32; off > 0; off >>= 1) {
        e += __shfl_xor(e, off, 64);
        p += __shfl_xor(p, off, 64);
    }
    if ((tid & 63) == 0) { s4[(tid >> 6) * 2] = e; s4[(tid >> 6) * 2 + 1] = p; }
    __syncthreads();
    if (tid == 0) { out[0] = s4[0] + s4[2]; out[1] = s4[1] + s4[3]; }
}

extern "C" void kernel_launch(void* const* d_in, const int* in_sizes, int n_in,
                              void* d_out, int out_size, void* d_ws, size_t ws_size,
                              hipStream_t stream)
{
    const float* g_emb  = (const float*)d_in[0];
    const float* W_ih   = (const float*)d_in[1];
    const float* W_hh   = (const float*)d_in[2];
    const float* b_ih   = (const float*)d_in[3];
    const float* b_hh   = (const float*)d_in[4];
    const float* ctx_W  = (const float*)d_in[5];
    const float* ctx_b  = (const float*)d_in[6];
    const float* left_W = (const float*)d_in[7];
    const float* left_b = (const float*)d_in[8];
    const int* config      = (const int*)d_in[9];
    const int* left_config = (const int*)d_in[10];
    float* out = (float*)d_out;
    float* ws  = (float*)d_ws;

    k_init<<<dim3(16), dim3(256), 0, stream>>>(ws);
    k_chain<<<dim3(NBLK), dim3(TPB), 0, stream>>>(g_emb, W_ih, W_hh, b_ih, b_hh, config, ws);
    k_heads<<<dim3(AL), dim3(256), 0, stream>>>(ctx_W, ctx_b, left_W, left_b,
                                                config, left_config, ws);
    k_reduce<<<dim3(1), dim3(128), 0, stream>>>(ws, out);
}

// Round 11
// 1394.602 us; speedup vs baseline: 1.4152x; 1.4152x over previous
//
#include <hip/hip_runtime.h>

#define HID 1024
#define AL  128
#define OPS 16
#define GS  32
#define NBLK 256
#define TPB  256

// ws layout (float offsets)
#define WS_OUTMAIN 0         // [128][1024]
#define WS_OUTGAP  131072    // [128][1024]
#define WS_PE      262144    // [128]
#define WS_PL      262272    // [128]
#define WS_PUB     262400    // uint2 pub[2 layers][2 parity][1024 units] = 8192 uints

__device__ __forceinline__ float sig_(float x) { return 1.0f / (1.0f + expf(-x)); }

// Coherence-point (L3/MALL) accessors: sc0 sc1 bypass L1 + non-coherent L2.
__device__ __forceinline__ void ld_coh_u4(uint4& d, const uint4* p) {
    asm volatile("global_load_dwordx4 %0, %1, off sc0 sc1" : "=v"(d) : "v"(p) : "memory");
}
__device__ __forceinline__ void st_coh_u2(uint2* p, uint2 v) {
    asm volatile("global_store_dwordx2 %0, %1, off sc0 sc1" :: "v"(p), "v"(v) : "memory");
}
// Drain outstanding vm ops; sched_barrier stops the compiler from hoisting
// dependent uses above the wait (rule #18).
__device__ __forceinline__ void wait_vm0() {
    asm volatile("s_waitcnt vmcnt(0)" ::: "memory");
    __builtin_amdgcn_sched_barrier(0);
}
// Record {h, tag=epoch^bits(h)}: validates both words, detects any tearing.
__device__ __forceinline__ bool rec_ok(const uint4& v, unsigned e) {
    return (v.y == (e ^ v.x)) && (v.w == (e ^ v.z));
}

__global__ void k_init(float* ws) {
    const int i = blockIdx.x * blockDim.x + threadIdx.x;
    if (i < 8192) ((unsigned*)(ws + WS_PUB))[i] = 0u;  // h=0, tag=0^bits(0)=0 -> epoch 0 valid
}

#define WIDX(l, r, k, c) ((((l) * 4 + (r)) * 8 + (k)) * 4 + (c))

// One LSTM layer-cell. The barrier IS the data: publish {h,tag} as one atomic
// 8B record; peers poll their 4 x-records + 4 recurrent-records until the tags
// validate, staging h straight into LDS. No separate flags, acks, or x-loads.
template<int LY>
__device__ __forceinline__ void cell(
    float (&wa)[256], const float (&bs)[2][4], float (&cst)[2],
    unsigned* pub, unsigned eSelf, unsigned eOther,
    bool useG, const float* g_emb,
    int tid, int lane, int u, float* lds_cat, float* snap)
{
    __syncthreads();   // all waves done READING lds_cat from the previous cell

    // ---- poll + stage: records 4*tid .. 4*tid+3 of each needed array ----
    const uint4* pubu4 = (const uint4*)pub;               // 1 uint4 = 2 records
    const uint4* br = pubu4 + ((unsigned)LY * 2u + (eSelf & 1u)) * 512u + 2 * tid;
    uint4 r0, r1;
    if (useG) {
        for (;;) {
            ld_coh_u4(r0, br); ld_coh_u4(r1, br + 1);
            wait_vm0();
            if (rec_ok(r0, eSelf) && rec_ok(r1, eSelf)) break;
        }
        ((float4*)lds_cat)[tid] = ((const float4*)g_emb)[tid];
    } else {
        const uint4* bx = pubu4 + ((unsigned)(1 - LY) * 2u + (eOther & 1u)) * 512u + 2 * tid;
        uint4 x0, x1;
        for (;;) {
            ld_coh_u4(x0, bx); ld_coh_u4(x1, bx + 1);
            ld_coh_u4(r0, br); ld_coh_u4(r1, br + 1);
            wait_vm0();
            if (rec_ok(x0, eOther) && rec_ok(x1, eOther) &&
                rec_ok(r0, eSelf)  && rec_ok(r1, eSelf)) break;
        }
        ((float4*)lds_cat)[tid] =
            make_float4(__uint_as_float(x0.x), __uint_as_float(x0.z),
                        __uint_as_float(x1.x), __uint_as_float(x1.z));
    }
    ((float4*)lds_cat)[256 + tid] =
        make_float4(__uint_as_float(r0.x), __uint_as_float(r0.z),
                    __uint_as_float(r1.x), __uint_as_float(r1.z));
    __syncthreads();

    // ---- dot: 4 gate rows, weights from AGPRs ----
    float acc[4] = {0.f, 0.f, 0.f, 0.f};
    const float4* l4 = (const float4*)lds_cat;
#pragma unroll
    for (int k = 0; k < 8; k++) {
        float4 v = l4[lane + 64 * k];   // contiguous 1KB per instr: conflict-free
#pragma unroll
        for (int r = 0; r < 4; r++) {
            float w0, w1, w2, w3;
            asm volatile("v_accvgpr_read_b32 %0, %1" : "=v"(w0) : "a"(wa[WIDX(LY, r, k, 0)]));
            asm volatile("v_accvgpr_read_b32 %0, %1" : "=v"(w1) : "a"(wa[WIDX(LY, r, k, 1)]));
            asm volatile("v_accvgpr_read_b32 %0, %1" : "=v"(w2) : "a"(wa[WIDX(LY, r, k, 2)]));
            asm volatile("v_accvgpr_read_b32 %0, %1" : "=v"(w3) : "a"(wa[WIDX(LY, r, k, 3)]));
            acc[r] += w0 * v.x + w1 * v.y + w2 * v.z + w3 * v.w;
        }
    }
#pragma unroll
    for (int off = 32; off > 0; off >>= 1) {
        acc[0] += __shfl_xor(acc[0], off, 64);
        acc[1] += __shfl_xor(acc[1], off, 64);
        acc[2] += __shfl_xor(acc[2], off, 64);
        acc[3] += __shfl_xor(acc[3], off, 64);
    }
    const float gi = sig_(acc[0] + bs[LY][0]);
    const float gf = sig_(acc[1] + bs[LY][1]);
    const float gg = tanhf(acc[2] + bs[LY][2]);
    const float go = sig_(acc[3] + bs[LY][3]);
    const float c  = gf * cst[LY] + gi * gg;
    cst[LY] = c;
    const float h = go * tanhf(c);

    // ---- publish: one atomic 8B self-validating record; no ack needed ----
    if (lane == 0) {
        const unsigned newE = eSelf + 1u;
        const unsigned hb = __float_as_uint(h);
        uint2 rec; rec.x = hb; rec.y = newE ^ hb;
        st_coh_u2((uint2*)pub + ((unsigned)LY * 2u + (newE & 1u)) * 1024u + u, rec);
        if (snap) snap[u] = h;   // plain store; next kernel reads after boundary
    }
}

__global__ __launch_bounds__(TPB, 1) void k_chain(
    const float* __restrict__ g_emb, const float* __restrict__ W_ih,
    const float* __restrict__ W_hh, const float* __restrict__ b_ih,
    const float* __restrict__ b_hh, const int* __restrict__ config, float* ws)
{
    const int tid  = threadIdx.x;
    const int bid  = blockIdx.x;
    const int lane = tid & 63;
    const int u    = bid * 4 + (tid >> 6);   // hidden unit owned by this wave

    float* OutMain = ws + WS_OUTMAIN;
    float* OutGap  = ws + WS_OUTGAP;
    unsigned* pub  = (unsigned*)(ws + WS_PUB);

    __shared__ float lds_cat[2048];
    __shared__ int   cfg_s[AL];

    // Persist weights in AGPRs: 256 fp32/lane (1 wave/SIMD -> 512-reg budget).
    float wa[256];
    float bs[2][4];
#pragma unroll
    for (int l = 0; l < 2; l++) {
#pragma unroll
        for (int r = 0; r < 4; r++) {
            const float* Wi = W_ih + (size_t)l * 4 * HID * HID + (size_t)(r * HID + u) * HID;
            const float* Wh = W_hh + (size_t)l * 4 * HID * HID + (size_t)(r * HID + u) * HID;
#pragma unroll
            for (int k = 0; k < 4; k++) {
                float4 t = *(const float4*)(Wi + 4 * lane + 256 * k);
                asm volatile("v_accvgpr_write_b32 %0, %1" : "=a"(wa[WIDX(l, r, k, 0)]) : "v"(t.x));
                asm volatile("v_accvgpr_write_b32 %0, %1" : "=a"(wa[WIDX(l, r, k, 1)]) : "v"(t.y));
                asm volatile("v_accvgpr_write_b32 %0, %1" : "=a"(wa[WIDX(l, r, k, 2)]) : "v"(t.z));
                asm volatile("v_accvgpr_write_b32 %0, %1" : "=a"(wa[WIDX(l, r, k, 3)]) : "v"(t.w));
            }
#pragma unroll
            for (int k = 0; k < 4; k++) {
                float4 t = *(const float4*)(Wh + 4 * lane + 256 * k);
                asm volatile("v_accvgpr_write_b32 %0, %1" : "=a"(wa[WIDX(l, r, k + 4, 0)]) : "v"(t.x));
                asm volatile("v_accvgpr_write_b32 %0, %1" : "=a"(wa[WIDX(l, r, k + 4, 1)]) : "v"(t.y));
                asm volatile("v_accvgpr_write_b32 %0, %1" : "=a"(wa[WIDX(l, r, k + 4, 2)]) : "v"(t.z));
                asm volatile("v_accvgpr_write_b32 %0, %1" : "=a"(wa[WIDX(l, r, k + 4, 3)]) : "v"(t.w));
            }
            bs[l][r] = b_ih[l * 4 * HID + r * HID + u] + b_hh[l * 4 * HID + r * HID + u];
        }
    }
    if (tid < AL) cfg_s[tid] = config[tid];
    __syncthreads();

    float cst[2] = {0.f, 0.f};
    unsigned e0 = 0, e1 = 0;   // published-cell counters per layer (identical on all blocks)
    bool first = true;

    for (int t = 0; t < AL; t++) {
        cell<0>(wa, bs, cst, pub, e0, e1, first, g_emb, tid, lane, u, lds_cat, nullptr);
        e0++; first = false;
        cell<1>(wa, bs, cst, pub, e1, e0, false, nullptr, tid, lane, u, lds_cat, OutMain + t * HID);
        e1++;
        if (cfg_s[t] == 1) {   // gap pass only matters when cfg == 1
            cell<0>(wa, bs, cst, pub, e0, e1, false, nullptr, tid, lane, u, lds_cat, nullptr);
            e0++;
            cell<1>(wa, bs, cst, pub, e1, e0, false, nullptr, tid, lane, u, lds_cat, OutGap + t * HID);
            e1++;
        }
    }
}

__global__ void k_heads(
    const float* __restrict__ ctx_W, const float* __restrict__ ctx_b,
    const float* __restrict__ left_W, const float* __restrict__ left_b,
    const int* __restrict__ config, const int* __restrict__ left_config, float* ws)
{
    const int t   = blockIdx.x;    // 128 blocks, one per step
    const int tid = threadIdx.x;   // 256 threads
    const float* o1 = ws + WS_OUTMAIN + (size_t)t * HID;
    const float* o2 = ws + WS_OUTGAP  + (size_t)t * HID;
    const int cfg = config[t];

    __shared__ float lgm[OPS];
    __shared__ float lgg[GS];

    float ent = 0.f, lp = 0.f;
    {   // main head: 16 rows, 16 threads/row
        const int g = tid >> 4, l16 = tid & 15;
        const float* wr = ctx_W + ((size_t)t * OPS + g) * HID;
        float a = 0.f;
#pragma unroll 4
        for (int k = 0; k < 16; k++) {
            float4 wv = *(const float4*)(wr + 4 * l16 + 64 * k);
            float4 xv = *(const float4*)(o1 + 4 * l16 + 64 * k);
            a += wv.x * xv.x + wv.y * xv.y + wv.z * xv.z + wv.w * xv.w;
        }
#pragma unroll
        for (int off = 1; off < 16; off <<= 1) a += __shfl_xor(a, off, 64);
        if (l16 == 0) lgm[g] = a + ctx_b[t * OPS + g];
    }
    __syncthreads();
    if (tid == 0) {
        float m = -1e30f;
        for (int g = 0; g < OPS; g++) m = fmaxf(m, lgm[g]);
        float s = 0.f;
        for (int g = 0; g < OPS; g++) s += expf(lgm[g] - m);
        const float lse = m + logf(s);
        for (int g = 0; g < OPS; g++) { float ls = lgm[g] - lse; ent -= expf(ls) * ls; }
        lp += lgm[cfg] - lse;
    }
    if (cfg == 1) {   // gap head: 32 rows, 8 threads/row
        const int g = tid >> 3, l8 = tid & 7;
        const float* wr = left_W + ((size_t)t * GS + g) * HID;
        float a = 0.f;
#pragma unroll 4
        for (int k = 0; k < 32; k++) {
            float4 wv = *(const float4*)(wr + 4 * l8 + 32 * k);
            float4 xv = *(const float4*)(o2 + 4 * l8 + 32 * k);
            a += wv.x * xv.x + wv.y * xv.y + wv.z * xv.z + wv.w * xv.w;
        }
#pragma unroll
        for (int off = 1; off < 8; off <<= 1) a += __shfl_xor(a, off, 64);
        if (l8 == 0) lgg[g] = a + left_b[t * GS + g];
        __syncthreads();
        if (tid == 0) {
            float m = -1e30f;
            for (int g = 0; g < GS; g++) m = fmaxf(m, lgg[g]);
            float s = 0.f;
            for (int g = 0; g < GS; g++) s += expf(lgg[g] - m);
            const float lse = m + logf(s);
            for (int g = 0; g < GS; g++) { float ls = lgg[g] - lse; ent -= expf(ls) * ls; }
            lp += lgg[left_config[t]] - lse;
        }
    }
    if (tid == 0) { ws[WS_PE + t] = ent; ws[WS_PL + t] = lp; }
}

__global__ void k_reduce(const float* __restrict__ ws, float* __restrict__ out) {
    const int tid = threadIdx.x;   // 128 threads, 2 waves
    __shared__ float s4[4];
    float e = ws[WS_PE + tid], p = ws[WS_PL + tid];
#pragma unroll
    for (int off = 32; off > 0; off >>= 1) {
        e += __shfl_xor(e, off, 64);
        p += __shfl_xor(p, off, 64);
    }
    if ((tid & 63) == 0) { s4[(tid >> 6) * 2] = e; s4[(tid >> 6) * 2 + 1] = p; }
    __syncthreads();
    if (tid == 0) { out[0] = s4[0] + s4[2]; out[1] = s4[1] + s4[3]; }
}

extern "C" void kernel_launch(void* const* d_in, const int* in_sizes, int n_in,
                              void* d_out, int out_size, void* d_ws, size_t ws_size,
                              hipStream_t stream)
{
    const float* g_emb  = (const float*)d_in[0];
    const float* W_ih   = (const float*)d_in[1];
    const float* W_hh   = (const float*)d_in[2];
    const float* b_ih   = (const float*)d_in[3];
    const float* b_hh   = (const float*)d_in[4];
    const float* ctx_W  = (const float*)d_in[5];
    const float* ctx_b  = (const float*)d_in[6];
    const float* left_W = (const float*)d_in[7];
    const float* left_b = (const float*)d_in[8];
    const int* config      = (const int*)d_in[9];
    const int* left_config = (const int*)d_in[10];
    float* out = (float*)d_out;
    float* ws  = (float*)d_ws;

    k_init<<<dim3(32), dim3(256), 0, stream>>>(ws);
    k_chain<<<dim3(NBLK), dim3(TPB), 0, stream>>>(g_emb, W_ih, W_hh, b_ih, b_hh, config, ws);
    k_heads<<<dim3(AL), dim3(256), 0, stream>>>(ctx_W, ctx_b, left_W, left_b,
                                                config, left_config, ws);
    k_reduce<<<dim3(1), dim3(128), 0, stream>>>(ws, out);
}